// Round 11
// baseline (152.980 us; speedup 1.0000x reference)
//
#include <hip/hip_runtime.h>

#define N_NODES 100000
#define N_EDGES 1600000
#define IN_C 128
#define HID_C 64
#define OUT_C 32

#define NBUCK 782        // ceil(100000 / 128) buckets of 128 nodes
#define NBLK_B 256       // edge-chunk blocks for bucket count/scatter
#define CHUNK 6250       // N_EDGES / NBLK_B (exact)
#define BSTRIDE 1024     // padded stride for bcnt/off tables
#define MAXPT 12         // per-thread reg capacity in CSR build (3072/bucket)

#define MF_BLKS 1563     // ceil(N_NODES / 64) MFMA-GEMM blocks (64 rows each)

typedef unsigned int uint;
typedef unsigned short ushort;
typedef __attribute__((ext_vector_type(8))) short bf16x8;
typedef __attribute__((ext_vector_type(4))) float f32x4;

__device__ inline ushort f2bf(float f) {   // RNE float->bf16
    uint u = __float_as_uint(f);
    u += 0x7fff + ((u >> 16) & 1);
    return (ushort)(u >> 16);
}
__device__ inline float bf2f(ushort h) {
    return __uint_as_float(((uint)h) << 16);
}

// ---------------- K1: per-block coarse bucket histogram (LDS atomics on ints) ----------------

__global__ __launch_bounds__(256) void k_bucket_count(const int* __restrict__ dst,
                                                      int* __restrict__ bcnt) {
    __shared__ int h[NBUCK];
    int t = threadIdx.x;
    for (int b = t; b < NBUCK; b += 256) h[b] = 0;
    __syncthreads();
    int base = blockIdx.x * CHUNK;
    int end = base + CHUNK;
    for (int i = base + t; i < end; i += 512) {
        int d0 = dst[i];
        int ok1 = (i + 256 < end);
        int d1 = ok1 ? dst[i + 256] : 0;
        atomicAdd(&h[d0 >> 7], 1);
        if (ok1) atomicAdd(&h[d1 >> 7], 1);
    }
    __syncthreads();
    for (int b = t; b < NBUCK; b += 256) bcnt[blockIdx.x * BSTRIDE + b] = h[b];
}

// ---------------- K2a: per-bucket column scan over 256 blocks -> off, total ----------------

__global__ __launch_bounds__(256) void k_col_scan(const int* __restrict__ bcnt,
                                                  int* __restrict__ off,
                                                  int* __restrict__ total) {
    __shared__ int ps[256];
    int t = threadIdx.x, b = blockIdx.x;
    int l = bcnt[t * BSTRIDE + b];
    ps[t] = l;
    __syncthreads();
    for (int o = 1; o < 256; o <<= 1) {
        int u = (t >= o) ? ps[t - o] : 0;
        __syncthreads();
        ps[t] += u;
        __syncthreads();
    }
    off[t * BSTRIDE + b] = ps[t] - l;  // exclusive prefix
    if (t == 255) total[b] = ps[255];
}

// ---------------- K2b: scan bucket totals -> bucket_start ----------------

__global__ __launch_bounds__(256) void k_bucket_scan(const int* __restrict__ total,
                                                     int* __restrict__ bucket_start,
                                                     int* __restrict__ row_start) {
    __shared__ int ps[256];
    int t = threadIdx.x;
    int v[4];
    int base = t * 4;
#pragma unroll
    for (int q = 0; q < 4; ++q) v[q] = (base + q < NBUCK) ? total[base + q] : 0;
    ps[t] = v[0] + v[1] + v[2] + v[3];
    __syncthreads();
    for (int o = 1; o < 256; o <<= 1) {
        int u = (t >= o) ? ps[t - o] : 0;
        __syncthreads();
        ps[t] += u;
        __syncthreads();
    }
    int run = (t > 0) ? ps[t - 1] : 0;
#pragma unroll
    for (int q = 0; q < 4; ++q) {
        if (base + q <= NBUCK) bucket_start[base + q] = run;
        run += v[q];
    }
    if (t == 0) row_start[N_NODES] = N_EDGES;
}

// ------- K3 fat kernel: blocks [0,256) scatter edges into buckets; rest do h1 = x@W1 (MFMA) -------

__global__ __launch_bounds__(256) void k_scatter_fat(const int* __restrict__ src,
                                                     const int* __restrict__ dst,
                                                     const int* __restrict__ bucket_start,
                                                     const int* __restrict__ off,
                                                     int* __restrict__ tmp,
                                                     const float* __restrict__ x,
                                                     const float* __restrict__ W1,
                                                     ushort* __restrict__ h1b) {
    __shared__ uint smu[4096];  // 16 KiB: scatter cursor table / W1 bf16 fragments
    int t = threadIdx.x;
    if (blockIdx.x < NBLK_B) {
        // bucket scatter: write window per (block, bucket) is disjoint
        int* cur = (int*)smu;
        for (int b = t; b < NBUCK; b += 256)
            cur[b] = bucket_start[b] + off[blockIdx.x * BSTRIDE + b];
        __syncthreads();
        int base = blockIdx.x * CHUNK;
        int end = base + CHUNK;
        // 2 independent edges in flight per thread per iteration
        for (int i = base + t; i < end; i += 512) {
            int s0 = src[i], d0 = dst[i];
            int ok1 = (i + 256 < end);
            int s1 = 0, d1 = 0;
            if (ok1) { s1 = src[i + 256]; d1 = dst[i + 256]; }
            int p0 = atomicAdd(&cur[d0 >> 7], 1);
            tmp[p0] = (s0 << 7) | (d0 & 127);
            if (ok1) {
                int p1 = atomicAdd(&cur[d1 >> 7], 1);
                tmp[p1] = (s1 << 7) | (d1 & 127);
            }
        }
    } else {
        // h1 = x @ W1 via mfma_f32_16x16x32_bf16. 64 rows/block, wave w -> rows w*16..w*16+15.
        // Fragment layouts: A row=lane&15, k=(lane>>4)*8+j; B k likewise, col=lane&15;
        // D col=lane&15, row=(lane>>4)*4+reg (guide-verified).
        int g = blockIdx.x - NBLK_B;
        // build W1 bf16 B-fragments in LDS: smu[((kt*4+ct)*64 + lane)*4 + dw]
#pragma unroll
        for (int i = 0; i < 16; ++i) {
            int lin = i * 256 + t;           // 0..4095
            int frag = lin >> 8;             // 0..15 = kt*4+ct
            int lane_ = (lin >> 2) & 63;
            int dw = lin & 3;
            int k = ((frag >> 2) << 5) + ((lane_ >> 4) << 3) + dw * 2;
            int c = ((frag & 3) << 4) + (lane_ & 15);
            smu[lin] = ((uint)f2bf(W1[(k + 1) * HID_C + c]) << 16) | f2bf(W1[k * HID_C + c]);
        }
        __syncthreads();
        int wave = t >> 6, lane = t & 63;
        int row0 = g * 64 + wave * 16;
        bf16x8 bfr[4][4];
#pragma unroll
        for (int kt = 0; kt < 4; ++kt)
#pragma unroll
            for (int ct = 0; ct < 4; ++ct)
                bfr[kt][ct] = *(bf16x8*)&smu[((kt * 4 + ct) * 64 + lane) * 4];
        int arow = row0 + (lane & 15);
        if (arow > N_NODES - 1) arow = N_NODES - 1;  // tail block: clamp loads, guard stores
        int kbase = (lane >> 4) * 8;
        f32x4 acc0 = {0.f, 0.f, 0.f, 0.f}, acc1 = {0.f, 0.f, 0.f, 0.f};
        f32x4 acc2 = {0.f, 0.f, 0.f, 0.f}, acc3 = {0.f, 0.f, 0.f, 0.f};
#pragma unroll
        for (int kt = 0; kt < 4; ++kt) {
            const float* xp = &x[arow * IN_C + kt * 32 + kbase];
            float4 u0 = *(const float4*)xp;
            float4 u1 = *(const float4*)(xp + 4);
            union { uint u[4]; bf16x8 v; } A;
            A.u[0] = ((uint)f2bf(u0.y) << 16) | f2bf(u0.x);
            A.u[1] = ((uint)f2bf(u0.w) << 16) | f2bf(u0.z);
            A.u[2] = ((uint)f2bf(u1.y) << 16) | f2bf(u1.x);
            A.u[3] = ((uint)f2bf(u1.w) << 16) | f2bf(u1.z);
            acc0 = __builtin_amdgcn_mfma_f32_16x16x32_bf16(A.v, bfr[kt][0], acc0, 0, 0, 0);
            acc1 = __builtin_amdgcn_mfma_f32_16x16x32_bf16(A.v, bfr[kt][1], acc1, 0, 0, 0);
            acc2 = __builtin_amdgcn_mfma_f32_16x16x32_bf16(A.v, bfr[kt][2], acc2, 0, 0, 0);
            acc3 = __builtin_amdgcn_mfma_f32_16x16x32_bf16(A.v, bfr[kt][3], acc3, 0, 0, 0);
        }
        int rbase = row0 + ((lane >> 4) << 2);
        int cb = lane & 15;
#pragma unroll
        for (int r = 0; r < 4; ++r) {
            int row = rbase + r;
            if (row < N_NODES) {
                h1b[row * HID_C + cb]      = f2bf(acc0[r]);
                h1b[row * HID_C + 16 + cb] = f2bf(acc1[r]);
                h1b[row * HID_C + 32 + cb] = f2bf(acc2[r]);
                h1b[row * HID_C + 48 + cb] = f2bf(acc3[r]);
            }
        }
    }
}

// ------- K4: per-bucket CSR build + h1 prescale (h~ = bf16(dinv*h1)) -------

__global__ __launch_bounds__(256) void k_csr_build(const int* __restrict__ bucket_start,
                                                   const int* __restrict__ tmp,
                                                   int* __restrict__ row_start,
                                                   int* __restrict__ eidx,
                                                   float* __restrict__ dinv,
                                                   uint* __restrict__ h1u) {
    __shared__ int h[128];
    __shared__ int cur[128];
    __shared__ float dl[128];
    int b = blockIdx.x, t = threadIdx.x;
    int e0 = bucket_start[b], e1 = bucket_start[b + 1];
    if (t < 128) h[t] = 0;
    int pk[MAXPT];
#pragma unroll
    for (int k = 0; k < MAXPT; ++k) {
        int i = e0 + k * 256 + t;
        pk[k] = (i < e1) ? tmp[i] : -1;
    }
    __syncthreads();
#pragma unroll
    for (int k = 0; k < MAXPT; ++k)
        if (pk[k] >= 0) atomicAdd(&h[pk[k] & 127], 1);
    for (int i = e0 + MAXPT * 256 + t; i < e1; i += 256)  // safety tail
        atomicAdd(&h[tmp[i] & 127], 1);
    __syncthreads();
    int d0 = (t < 128) ? h[t] : 0;
    for (int o = 1; o < 128; o <<= 1) {
        int u = (t >= o && t < 128) ? h[t - o] : 0;
        __syncthreads();
        if (t < 128) h[t] += u;
        __syncthreads();
    }
    int g = b * 128 + t;
    if (t < 128 && g < N_NODES) {
        int ex = h[t] - d0;
        row_start[g] = e0 + ex;
        cur[t]       = e0 + ex;
        float dv = rsqrtf((float)(d0 + 1));  // +1 self loop
        dinv[g] = dv;
        dl[t] = dv;
    }
    __syncthreads();
#pragma unroll
    for (int k = 0; k < MAXPT; ++k)
        if (pk[k] >= 0) {
            int p = atomicAdd(&cur[pk[k] & 127], 1);
            eidx[p] = pk[k] >> 7;
        }
    for (int i = e0 + MAXPT * 256 + t; i < e1; i += 256) {
        int v = tmp[i];
        int p = atomicAdd(&cur[v & 127], 1);
        eidx[p] = v >> 7;
    }
    // prescale this bucket's h1 rows by dinv (bf16x2 per uint)
    int bu = b * 128 * (HID_C / 2);
    for (int i = t; i < 128 * (HID_C / 2); i += 256) {
        int rl = i >> 5;
        int gg = b * 128 + rl;
        if (gg < N_NODES) {
            float dv = dl[rl];
            uint v = h1u[bu + i];
            float lo = __uint_as_float(v << 16) * dv;
            float hi = __uint_as_float(v & 0xffff0000u) * dv;
            h1u[bu + i] = ((uint)f2bf(hi) << 16) | f2bf(lo);
        }
    }
}

// ------- K5: gather layer 1 (prescaled h~) + relu + FUSED gemm2 -> hs2 (bf16) -------
// 256 thr; 4 node-groups of 8 per block (W2 staged once); 32 lanes/node.
// 16-deep edge unroll: ~avg degree, maximizes outstanding loads per thread.

__global__ __launch_bounds__(256) void k_gather1f(const int* __restrict__ row_start,
                                                  const int* __restrict__ eidx,
                                                  const uint* __restrict__ h1u,
                                                  const float* __restrict__ dinv,
                                                  const float* __restrict__ b1,
                                                  const float* __restrict__ W2,
                                                  ushort* __restrict__ hs2b) {
    __shared__ float a1s[8][HID_C];       // 2 KiB
    __shared__ float W2s[HID_C * OUT_C];  // 8 KiB
    int t = threadIdx.x;
    for (int i = t; i < HID_C * OUT_C; i += 256) W2s[i] = W2[i];
    int sub = t & 31;
    int r = t >> 5;  // 0..7
    float2 bb = *(const float2*)&b1[sub * 2];

    for (int g = 0; g < 4; ++g) {
        int node = (blockIdx.x * 4 + g) * 8 + r;  // N_NODES = 3125*4*8 exact
        float dn = dinv[node];
        int rs = row_start[node];
        int re = row_start[node + 1];
        uint su = h1u[node * 32 + sub];           // self term: already dinv-scaled
        float accx = __uint_as_float(su << 16);
        float accy = __uint_as_float(su & 0xffff0000u);
        int j = rs;
        for (; j + 15 < re; j += 16) {
            int s[16];
            uint u[16];
#pragma unroll
            for (int q = 0; q < 16; ++q) s[q] = eidx[j + q];
#pragma unroll
            for (int q = 0; q < 16; ++q) u[q] = h1u[s[q] * 32 + sub];
            float ax = 0.f, ay = 0.f;
#pragma unroll
            for (int q = 0; q < 16; ++q) {
                ax += __uint_as_float(u[q] << 16);
                ay += __uint_as_float(u[q] & 0xffff0000u);
            }
            accx += ax; accy += ay;
        }
        for (; j + 3 < re; j += 4) {
            int s0 = eidx[j], s1 = eidx[j + 1], s2 = eidx[j + 2], s3 = eidx[j + 3];
            uint u0 = h1u[s0 * 32 + sub], u1 = h1u[s1 * 32 + sub];
            uint u2 = h1u[s2 * 32 + sub], u3 = h1u[s3 * 32 + sub];
            accx += (__uint_as_float(u0 << 16) + __uint_as_float(u1 << 16))
                  + (__uint_as_float(u2 << 16) + __uint_as_float(u3 << 16));
            accy += (__uint_as_float(u0 & 0xffff0000u) + __uint_as_float(u1 & 0xffff0000u))
                  + (__uint_as_float(u2 & 0xffff0000u) + __uint_as_float(u3 & 0xffff0000u));
        }
        for (; j < re; ++j) {
            uint u = h1u[eidx[j] * 32 + sub];
            accx += __uint_as_float(u << 16);
            accy += __uint_as_float(u & 0xffff0000u);
        }
        __syncthreads();  // a1s free (W2 staged / previous gemm2 done)
        a1s[r][sub * 2 + 0] = fmaxf(dn * accx + bb.x, 0.f);
        a1s[r][sub * 2 + 1] = fmaxf(dn * accy + bb.y, 0.f);
        __syncthreads();

        // fused gemm2: thread (r, o=sub): hs2[node][o] = dn * sum_k a1s[r][k] * W2[k][o]
        float sum = 0.f;
#pragma unroll 8
        for (int k = 0; k < HID_C; ++k)
            sum += a1s[r][k] * W2s[k * OUT_C + sub];
        hs2b[node * OUT_C + sub] = f2bf(dn * sum);
    }
}

// ------- K6: gather layer 2 (bf16 hs2, prescaled) + epilogue -> out -------
// 256 thr, 8 nodes/block, 32 lanes/node (lane = out channel). 16-deep unroll.

__global__ __launch_bounds__(256) void k_gather2(const int* __restrict__ row_start,
                                                 const int* __restrict__ eidx,
                                                 const ushort* __restrict__ hs2b,
                                                 const float* __restrict__ dinv,
                                                 const float* __restrict__ b2,
                                                 float* __restrict__ out) {
    int t = threadIdx.x;
    int sub = t & 31;
    int node = blockIdx.x * 8 + (t >> 5);  // N_NODES divisible by 8

    float dn = dinv[node];
    int rs = row_start[node];
    int re = row_start[node + 1];
    float acc = bf2f(hs2b[node * OUT_C + sub]);  // self loop
    int j = rs;
    for (; j + 15 < re; j += 16) {
        int s[16];
        float v[16];
#pragma unroll
        for (int q = 0; q < 16; ++q) s[q] = eidx[j + q];
#pragma unroll
        for (int q = 0; q < 16; ++q) v[q] = bf2f(hs2b[s[q] * OUT_C + sub]);
        float a = 0.f;
#pragma unroll
        for (int q = 0; q < 16; ++q) a += v[q];
        acc += a;
    }
    for (; j + 3 < re; j += 4) {
        int s0 = eidx[j], s1 = eidx[j + 1], s2 = eidx[j + 2], s3 = eidx[j + 3];
        float v0 = bf2f(hs2b[s0 * OUT_C + sub]);
        float v1 = bf2f(hs2b[s1 * OUT_C + sub]);
        float v2 = bf2f(hs2b[s2 * OUT_C + sub]);
        float v3 = bf2f(hs2b[s3 * OUT_C + sub]);
        acc += (v0 + v1) + (v2 + v3);
    }
    for (; j < re; ++j) acc += bf2f(hs2b[eidx[j] * OUT_C + sub]);

    out[node * OUT_C + sub] = dn * acc + b2[sub];
}

extern "C" void kernel_launch(void* const* d_in, const int* in_sizes, int n_in,
                              void* d_out, int out_size, void* d_ws, size_t ws_size,
                              hipStream_t stream) {
    const float* x  = (const float*)d_in[0];
    const int* ei   = (const int*)d_in[1];   // [2, E]: src then dst
    const float* W1 = (const float*)d_in[2];
    const float* b1 = (const float*)d_in[3];
    const float* W2 = (const float*)d_in[4];
    const float* b2 = (const float*)d_in[5];
    float* out = (float*)d_out;

    const int* src = ei;
    const int* dst = ei + N_EDGES;

    // workspace layout (bytes), total ~34.9 MB
    char* ws = (char*)d_ws;
    int*    row_start    = (int*)(ws + 0);            //   400,128 (N+1 ints)
    float*  dinv         = (float*)(ws + 400128);     //   400,128
    int*    bucket_start = (int*)(ws + 800256);       //     4,096
    int*    total        = (int*)(ws + 804352);       //     4,096
    int*    bcnt         = (int*)(ws + 808448);       // 1,048,576
    int*    off          = (int*)(ws + 1857024);      // 1,048,576
    int*    eidx         = (int*)(ws + 2905600);      // 6,400,000
    int*    tmp          = (int*)(ws + 9305600);      // 6,400,000
    ushort* h1b          = (ushort*)(ws + 15705600);  // 12,800,000 (bf16)
    ushort* hs2b         = (ushort*)(ws + 28505600);  //  6,400,000 (bf16)

    k_bucket_count<<<NBLK_B, 256, 0, stream>>>(dst, bcnt);
    k_col_scan<<<NBUCK, 256, 0, stream>>>(bcnt, off, total);
    k_bucket_scan<<<1, 256, 0, stream>>>(total, bucket_start, row_start);

    k_scatter_fat<<<NBLK_B + MF_BLKS, 256, 0, stream>>>(src, dst, bucket_start, off,
                                                        tmp, x, W1, h1b);
    k_csr_build<<<NBUCK, 256, 0, stream>>>(bucket_start, tmp, row_start, eidx, dinv,
                                           (uint*)h1b);

    k_gather1f<<<N_NODES / 32, 256, 0, stream>>>(row_start, eidx, (const uint*)h1b,
                                                 dinv, b1, W2, hs2b);
    k_gather2<<<N_NODES / 8, 256, 0, stream>>>(row_start, eidx, hs2b, dinv, b2, out);
}

// Round 12
// 146.391 us; speedup vs baseline: 1.0450x; 1.0450x over previous
//
#include <hip/hip_runtime.h>

#define N_NODES 100000
#define N_EDGES 1600000
#define IN_C 128
#define HID_C 64
#define OUT_C 32

#define NBUCK 782        // ceil(100000 / 128) buckets of 128 nodes
#define NBLK_B 256       // edge-chunk blocks for bucket count/scatter
#define CHUNK 6250       // N_EDGES / NBLK_B (exact)
#define BSTRIDE 1024     // padded stride for bcnt/off tables
#define MAXPT 12         // per-thread reg capacity in CSR build (3072/bucket)

#define MF_BLKS 782      // ceil(N_NODES / 128) MFMA-GEMM blocks (128 rows each)

typedef unsigned int uint;
typedef unsigned short ushort;
typedef __attribute__((ext_vector_type(8))) short bf16x8;
typedef __attribute__((ext_vector_type(4))) float f32x4;

__device__ inline ushort f2bf(float f) {   // RNE float->bf16
    uint u = __float_as_uint(f);
    u += 0x7fff + ((u >> 16) & 1);
    return (ushort)(u >> 16);
}
__device__ inline float bf2f(ushort h) {
    return __uint_as_float(((uint)h) << 16);
}

// ---------------- K1: per-block coarse bucket histogram (LDS atomics on ints) ----------------

__global__ __launch_bounds__(256) void k_bucket_count(const int* __restrict__ dst,
                                                      int* __restrict__ bcnt) {
    __shared__ int h[NBUCK];
    int t = threadIdx.x;
    for (int b = t; b < NBUCK; b += 256) h[b] = 0;
    __syncthreads();
    int base = blockIdx.x * CHUNK;
    int end = base + CHUNK;
    for (int i = base + t; i < end; i += 512) {
        int d0 = dst[i];
        int ok1 = (i + 256 < end);
        int d1 = ok1 ? dst[i + 256] : 0;
        atomicAdd(&h[d0 >> 7], 1);
        if (ok1) atomicAdd(&h[d1 >> 7], 1);
    }
    __syncthreads();
    for (int b = t; b < NBUCK; b += 256) bcnt[blockIdx.x * BSTRIDE + b] = h[b];
}

// ---------------- K2a: per-bucket column scan over 256 blocks -> off, total ----------------

__global__ __launch_bounds__(256) void k_col_scan(const int* __restrict__ bcnt,
                                                  int* __restrict__ off,
                                                  int* __restrict__ total) {
    __shared__ int ps[256];
    int t = threadIdx.x, b = blockIdx.x;
    int l = bcnt[t * BSTRIDE + b];
    ps[t] = l;
    __syncthreads();
    for (int o = 1; o < 256; o <<= 1) {
        int u = (t >= o) ? ps[t - o] : 0;
        __syncthreads();
        ps[t] += u;
        __syncthreads();
    }
    off[t * BSTRIDE + b] = ps[t] - l;  // exclusive prefix
    if (t == 255) total[b] = ps[255];
}

// ---------------- K2b: scan bucket totals -> bucket_start ----------------

__global__ __launch_bounds__(256) void k_bucket_scan(const int* __restrict__ total,
                                                     int* __restrict__ bucket_start,
                                                     int* __restrict__ row_start) {
    __shared__ int ps[256];
    int t = threadIdx.x;
    int v[4];
    int base = t * 4;
#pragma unroll
    for (int q = 0; q < 4; ++q) v[q] = (base + q < NBUCK) ? total[base + q] : 0;
    ps[t] = v[0] + v[1] + v[2] + v[3];
    __syncthreads();
    for (int o = 1; o < 256; o <<= 1) {
        int u = (t >= o) ? ps[t - o] : 0;
        __syncthreads();
        ps[t] += u;
        __syncthreads();
    }
    int run = (t > 0) ? ps[t - 1] : 0;
#pragma unroll
    for (int q = 0; q < 4; ++q) {
        if (base + q <= NBUCK) bucket_start[base + q] = run;
        run += v[q];
    }
    if (t == 0) row_start[N_NODES] = N_EDGES;
}

// ------- K3 fat kernel: blocks [0,256) scatter edges into buckets; rest do h1 = x@W1 (MFMA) -------

__global__ __launch_bounds__(256) void k_scatter_fat(const int* __restrict__ src,
                                                     const int* __restrict__ dst,
                                                     const int* __restrict__ bucket_start,
                                                     const int* __restrict__ off,
                                                     int* __restrict__ tmp,
                                                     const float* __restrict__ x,
                                                     const float* __restrict__ W1,
                                                     ushort* __restrict__ h1b) {
    __shared__ uint smu[4096];  // 16 KiB: scatter cursor table / W1 bf16 fragments
    int t = threadIdx.x;
    if (blockIdx.x < NBLK_B) {
        // bucket scatter: write window per (block, bucket) is disjoint
        int* cur = (int*)smu;
        for (int b = t; b < NBUCK; b += 256)
            cur[b] = bucket_start[b] + off[blockIdx.x * BSTRIDE + b];
        __syncthreads();
        int base = blockIdx.x * CHUNK;
        int end = base + CHUNK;
        // 2 independent edges in flight per thread per iteration
        for (int i = base + t; i < end; i += 512) {
            int s0 = src[i], d0 = dst[i];
            int ok1 = (i + 256 < end);
            int s1 = 0, d1 = 0;
            if (ok1) { s1 = src[i + 256]; d1 = dst[i + 256]; }
            int p0 = atomicAdd(&cur[d0 >> 7], 1);
            tmp[p0] = (s0 << 7) | (d0 & 127);
            if (ok1) {
                int p1 = atomicAdd(&cur[d1 >> 7], 1);
                tmp[p1] = (s1 << 7) | (d1 & 127);
            }
        }
    } else {
        // h1 = x @ W1 via mfma_f32_16x16x32_bf16. 128 rows/block (2 row-groups per
        // W1 staging). Fragment layouts: A row=lane&15, k=(lane>>4)*8+j; B likewise,
        // col=lane&15; D col=lane&15, row=(lane>>4)*4+reg (guide-verified).
        int g = blockIdx.x - NBLK_B;
        // build W1 bf16 B-fragments in LDS: smu[((kt*4+ct)*64 + lane)*4 + dw]
#pragma unroll
        for (int i = 0; i < 16; ++i) {
            int lin = i * 256 + t;           // 0..4095
            int frag = lin >> 8;             // 0..15 = kt*4+ct
            int lane_ = (lin >> 2) & 63;
            int dw = lin & 3;
            int k = ((frag >> 2) << 5) + ((lane_ >> 4) << 3) + dw * 2;
            int c = ((frag & 3) << 4) + (lane_ & 15);
            smu[lin] = ((uint)f2bf(W1[(k + 1) * HID_C + c]) << 16) | f2bf(W1[k * HID_C + c]);
        }
        __syncthreads();
        int wave = t >> 6, lane = t & 63;
        bf16x8 bfr[4][4];
#pragma unroll
        for (int kt = 0; kt < 4; ++kt)
#pragma unroll
            for (int ct = 0; ct < 4; ++ct)
                bfr[kt][ct] = *(bf16x8*)&smu[((kt * 4 + ct) * 64 + lane) * 4];
        int kbase = (lane >> 4) * 8;
#pragma unroll
        for (int it = 0; it < 2; ++it) {
            int row0 = g * 128 + it * 64 + wave * 16;
            int arow = row0 + (lane & 15);
            if (arow > N_NODES - 1) arow = N_NODES - 1;  // tail: clamp loads, guard stores
            f32x4 acc0 = {0.f, 0.f, 0.f, 0.f}, acc1 = {0.f, 0.f, 0.f, 0.f};
            f32x4 acc2 = {0.f, 0.f, 0.f, 0.f}, acc3 = {0.f, 0.f, 0.f, 0.f};
#pragma unroll
            for (int kt = 0; kt < 4; ++kt) {
                const float* xp = &x[arow * IN_C + kt * 32 + kbase];
                float4 u0 = *(const float4*)xp;
                float4 u1 = *(const float4*)(xp + 4);
                union { uint u[4]; bf16x8 v; } A;
                A.u[0] = ((uint)f2bf(u0.y) << 16) | f2bf(u0.x);
                A.u[1] = ((uint)f2bf(u0.w) << 16) | f2bf(u0.z);
                A.u[2] = ((uint)f2bf(u1.y) << 16) | f2bf(u1.x);
                A.u[3] = ((uint)f2bf(u1.w) << 16) | f2bf(u1.z);
                acc0 = __builtin_amdgcn_mfma_f32_16x16x32_bf16(A.v, bfr[kt][0], acc0, 0, 0, 0);
                acc1 = __builtin_amdgcn_mfma_f32_16x16x32_bf16(A.v, bfr[kt][1], acc1, 0, 0, 0);
                acc2 = __builtin_amdgcn_mfma_f32_16x16x32_bf16(A.v, bfr[kt][2], acc2, 0, 0, 0);
                acc3 = __builtin_amdgcn_mfma_f32_16x16x32_bf16(A.v, bfr[kt][3], acc3, 0, 0, 0);
            }
            int rbase = row0 + ((lane >> 4) << 2);
            int cb = lane & 15;
#pragma unroll
            for (int r = 0; r < 4; ++r) {
                int row = rbase + r;
                if (row < N_NODES) {
                    h1b[row * HID_C + cb]      = f2bf(acc0[r]);
                    h1b[row * HID_C + 16 + cb] = f2bf(acc1[r]);
                    h1b[row * HID_C + 32 + cb] = f2bf(acc2[r]);
                    h1b[row * HID_C + 48 + cb] = f2bf(acc3[r]);
                }
            }
        }
    }
}

// ------- K4: per-bucket CSR build + h1 prescale (h~ = bf16(dinv*h1)) -------

__global__ __launch_bounds__(256) void k_csr_build(const int* __restrict__ bucket_start,
                                                   const int* __restrict__ tmp,
                                                   int* __restrict__ row_start,
                                                   int* __restrict__ eidx,
                                                   float* __restrict__ dinv,
                                                   uint* __restrict__ h1u) {
    __shared__ int h[128];
    __shared__ int cur[128];
    __shared__ float dl[128];
    int b = blockIdx.x, t = threadIdx.x;
    int e0 = bucket_start[b], e1 = bucket_start[b + 1];
    if (t < 128) h[t] = 0;
    int pk[MAXPT];
#pragma unroll
    for (int k = 0; k < MAXPT; ++k) {
        int i = e0 + k * 256 + t;
        pk[k] = (i < e1) ? tmp[i] : -1;
    }
    __syncthreads();
#pragma unroll
    for (int k = 0; k < MAXPT; ++k)
        if (pk[k] >= 0) atomicAdd(&h[pk[k] & 127], 1);
    for (int i = e0 + MAXPT * 256 + t; i < e1; i += 256)  // safety tail
        atomicAdd(&h[tmp[i] & 127], 1);
    __syncthreads();
    int d0 = (t < 128) ? h[t] : 0;
    for (int o = 1; o < 128; o <<= 1) {
        int u = (t >= o && t < 128) ? h[t - o] : 0;
        __syncthreads();
        if (t < 128) h[t] += u;
        __syncthreads();
    }
    int g = b * 128 + t;
    if (t < 128 && g < N_NODES) {
        int ex = h[t] - d0;
        row_start[g] = e0 + ex;
        cur[t]       = e0 + ex;
        float dv = rsqrtf((float)(d0 + 1));  // +1 self loop
        dinv[g] = dv;
        dl[t] = dv;
    }
    __syncthreads();
#pragma unroll
    for (int k = 0; k < MAXPT; ++k)
        if (pk[k] >= 0) {
            int p = atomicAdd(&cur[pk[k] & 127], 1);
            eidx[p] = pk[k] >> 7;
        }
    for (int i = e0 + MAXPT * 256 + t; i < e1; i += 256) {
        int v = tmp[i];
        int p = atomicAdd(&cur[v & 127], 1);
        eidx[p] = v >> 7;
    }
    // prescale this bucket's h1 rows by dinv (bf16x2 per uint)
    int bu = b * 128 * (HID_C / 2);
    for (int i = t; i < 128 * (HID_C / 2); i += 256) {
        int rl = i >> 5;
        int gg = b * 128 + rl;
        if (gg < N_NODES) {
            float dv = dl[rl];
            uint v = h1u[bu + i];
            float lo = __uint_as_float(v << 16) * dv;
            float hi = __uint_as_float(v & 0xffff0000u) * dv;
            h1u[bu + i] = ((uint)f2bf(hi) << 16) | f2bf(lo);
        }
    }
}

// ------- K5: gather layer 1 (prescaled h~) + relu + FUSED gemm2 -> hs2 (bf16) -------
// 256 thr; 4 node-groups of 8 per block (W2 staged once); 32 lanes/node.
// 8-deep edge unroll (round-10 form: deeper unroll measured slower).

__global__ __launch_bounds__(256) void k_gather1f(const int* __restrict__ row_start,
                                                  const int* __restrict__ eidx,
                                                  const uint* __restrict__ h1u,
                                                  const float* __restrict__ dinv,
                                                  const float* __restrict__ b1,
                                                  const float* __restrict__ W2,
                                                  ushort* __restrict__ hs2b) {
    __shared__ float a1s[8][HID_C];       // 2 KiB
    __shared__ float W2s[HID_C * OUT_C];  // 8 KiB
    int t = threadIdx.x;
    for (int i = t; i < HID_C * OUT_C; i += 256) W2s[i] = W2[i];
    int sub = t & 31;
    int r = t >> 5;  // 0..7
    float2 bb = *(const float2*)&b1[sub * 2];

    for (int g = 0; g < 4; ++g) {
        int node = (blockIdx.x * 4 + g) * 8 + r;  // N_NODES = 3125*4*8 exact
        float dn = dinv[node];
        int rs = row_start[node];
        int re = row_start[node + 1];
        uint su = h1u[node * 32 + sub];           // self term: already dinv-scaled
        float accx = __uint_as_float(su << 16);
        float accy = __uint_as_float(su & 0xffff0000u);
        int j = rs;
        for (; j + 7 < re; j += 8) {
            int s0 = eidx[j],     s1 = eidx[j + 1], s2 = eidx[j + 2], s3 = eidx[j + 3];
            int s4 = eidx[j + 4], s5 = eidx[j + 5], s6 = eidx[j + 6], s7 = eidx[j + 7];
            uint u0 = h1u[s0 * 32 + sub], u1 = h1u[s1 * 32 + sub];
            uint u2 = h1u[s2 * 32 + sub], u3 = h1u[s3 * 32 + sub];
            uint u4 = h1u[s4 * 32 + sub], u5 = h1u[s5 * 32 + sub];
            uint u6 = h1u[s6 * 32 + sub], u7 = h1u[s7 * 32 + sub];
            accx += (__uint_as_float(u0 << 16) + __uint_as_float(u1 << 16))
                  + (__uint_as_float(u2 << 16) + __uint_as_float(u3 << 16))
                  + (__uint_as_float(u4 << 16) + __uint_as_float(u5 << 16))
                  + (__uint_as_float(u6 << 16) + __uint_as_float(u7 << 16));
            accy += (__uint_as_float(u0 & 0xffff0000u) + __uint_as_float(u1 & 0xffff0000u))
                  + (__uint_as_float(u2 & 0xffff0000u) + __uint_as_float(u3 & 0xffff0000u))
                  + (__uint_as_float(u4 & 0xffff0000u) + __uint_as_float(u5 & 0xffff0000u))
                  + (__uint_as_float(u6 & 0xffff0000u) + __uint_as_float(u7 & 0xffff0000u));
        }
        for (; j + 3 < re; j += 4) {
            int s0 = eidx[j], s1 = eidx[j + 1], s2 = eidx[j + 2], s3 = eidx[j + 3];
            uint u0 = h1u[s0 * 32 + sub], u1 = h1u[s1 * 32 + sub];
            uint u2 = h1u[s2 * 32 + sub], u3 = h1u[s3 * 32 + sub];
            accx += (__uint_as_float(u0 << 16) + __uint_as_float(u1 << 16))
                  + (__uint_as_float(u2 << 16) + __uint_as_float(u3 << 16));
            accy += (__uint_as_float(u0 & 0xffff0000u) + __uint_as_float(u1 & 0xffff0000u))
                  + (__uint_as_float(u2 & 0xffff0000u) + __uint_as_float(u3 & 0xffff0000u));
        }
        for (; j < re; ++j) {
            uint u = h1u[eidx[j] * 32 + sub];
            accx += __uint_as_float(u << 16);
            accy += __uint_as_float(u & 0xffff0000u);
        }
        __syncthreads();  // a1s free (W2 staged / previous gemm2 done)
        a1s[r][sub * 2 + 0] = fmaxf(dn * accx + bb.x, 0.f);
        a1s[r][sub * 2 + 1] = fmaxf(dn * accy + bb.y, 0.f);
        __syncthreads();

        // fused gemm2: thread (r, o=sub): hs2[node][o] = dn * sum_k a1s[r][k] * W2[k][o]
        float sum = 0.f;
#pragma unroll 8
        for (int k = 0; k < HID_C; ++k)
            sum += a1s[r][k] * W2s[k * OUT_C + sub];
        hs2b[node * OUT_C + sub] = f2bf(dn * sum);
    }
}

// ------- K6: gather layer 2 (bf16 hs2, prescaled) + epilogue -> out -------
// 256 thr, 8 nodes/block, 32 lanes/node (lane = out channel). 8-deep unroll.

__global__ __launch_bounds__(256) void k_gather2(const int* __restrict__ row_start,
                                                 const int* __restrict__ eidx,
                                                 const ushort* __restrict__ hs2b,
                                                 const float* __restrict__ dinv,
                                                 const float* __restrict__ b2,
                                                 float* __restrict__ out) {
    int t = threadIdx.x;
    int sub = t & 31;
    int node = blockIdx.x * 8 + (t >> 5);  // N_NODES divisible by 8

    float dn = dinv[node];
    int rs = row_start[node];
    int re = row_start[node + 1];
    float acc = bf2f(hs2b[node * OUT_C + sub]);  // self loop
    int j = rs;
    for (; j + 7 < re; j += 8) {
        int s0 = eidx[j],     s1 = eidx[j + 1], s2 = eidx[j + 2], s3 = eidx[j + 3];
        int s4 = eidx[j + 4], s5 = eidx[j + 5], s6 = eidx[j + 6], s7 = eidx[j + 7];
        float v0 = bf2f(hs2b[s0 * OUT_C + sub]);
        float v1 = bf2f(hs2b[s1 * OUT_C + sub]);
        float v2 = bf2f(hs2b[s2 * OUT_C + sub]);
        float v3 = bf2f(hs2b[s3 * OUT_C + sub]);
        float v4 = bf2f(hs2b[s4 * OUT_C + sub]);
        float v5 = bf2f(hs2b[s5 * OUT_C + sub]);
        float v6 = bf2f(hs2b[s6 * OUT_C + sub]);
        float v7 = bf2f(hs2b[s7 * OUT_C + sub]);
        acc += ((v0 + v1) + (v2 + v3)) + ((v4 + v5) + (v6 + v7));
    }
    for (; j + 3 < re; j += 4) {
        int s0 = eidx[j], s1 = eidx[j + 1], s2 = eidx[j + 2], s3 = eidx[j + 3];
        float v0 = bf2f(hs2b[s0 * OUT_C + sub]);
        float v1 = bf2f(hs2b[s1 * OUT_C + sub]);
        float v2 = bf2f(hs2b[s2 * OUT_C + sub]);
        float v3 = bf2f(hs2b[s3 * OUT_C + sub]);
        acc += (v0 + v1) + (v2 + v3);
    }
    for (; j < re; ++j) acc += bf2f(hs2b[eidx[j] * OUT_C + sub]);

    out[node * OUT_C + sub] = dn * acc + b2[sub];
}

extern "C" void kernel_launch(void* const* d_in, const int* in_sizes, int n_in,
                              void* d_out, int out_size, void* d_ws, size_t ws_size,
                              hipStream_t stream) {
    const float* x  = (const float*)d_in[0];
    const int* ei   = (const int*)d_in[1];   // [2, E]: src then dst
    const float* W1 = (const float*)d_in[2];
    const float* b1 = (const float*)d_in[3];
    const float* W2 = (const float*)d_in[4];
    const float* b2 = (const float*)d_in[5];
    float* out = (float*)d_out;

    const int* src = ei;
    const int* dst = ei + N_EDGES;

    // workspace layout (bytes), total ~34.9 MB
    char* ws = (char*)d_ws;
    int*    row_start    = (int*)(ws + 0);            //   400,128 (N+1 ints)
    float*  dinv         = (float*)(ws + 400128);     //   400,128
    int*    bucket_start = (int*)(ws + 800256);       //     4,096
    int*    total        = (int*)(ws + 804352);       //     4,096
    int*    bcnt         = (int*)(ws + 808448);       // 1,048,576
    int*    off          = (int*)(ws + 1857024);      // 1,048,576
    int*    eidx         = (int*)(ws + 2905600);      // 6,400,000
    int*    tmp          = (int*)(ws + 9305600);      // 6,400,000
    ushort* h1b          = (ushort*)(ws + 15705600);  // 12,800,000 (bf16)
    ushort* hs2b         = (ushort*)(ws + 28505600);  //  6,400,000 (bf16)

    k_bucket_count<<<NBLK_B, 256, 0, stream>>>(dst, bcnt);
    k_col_scan<<<NBUCK, 256, 0, stream>>>(bcnt, off, total);
    k_bucket_scan<<<1, 256, 0, stream>>>(total, bucket_start, row_start);

    k_scatter_fat<<<NBLK_B + MF_BLKS, 256, 0, stream>>>(src, dst, bucket_start, off,
                                                        tmp, x, W1, h1b);
    k_csr_build<<<NBUCK, 256, 0, stream>>>(bucket_start, tmp, row_start, eidx, dinv,
                                           (uint*)h1b);

    k_gather1f<<<N_NODES / 32, 256, 0, stream>>>(row_start, eidx, (const uint*)h1b,
                                                 dinv, b1, W2, hs2b);
    k_gather2<<<N_NODES / 8, 256, 0, stream>>>(row_start, eidx, hs2b, dinv, b2, out);
}

// Round 13
// 138.726 us; speedup vs baseline: 1.1027x; 1.0553x over previous
//
#include <hip/hip_runtime.h>

#define N_NODES 100000
#define N_EDGES 1600000
#define IN_C 128
#define HID_C 64
#define OUT_C 32

#define NBUCK 782        // ceil(100000 / 128) buckets of 128 nodes
#define NBLK_B 256       // edge-chunk blocks for the scatter branch
#define CHUNK 6250       // N_EDGES / NBLK_B (exact)
#define CAP 2560         // fixed tmp capacity per bucket (mean 2048, +11 sigma)
#define MAXPT 12         // per-thread reg capacity in CSR build (3072 >= CAP)

#define MF_BLKS 782      // ceil(N_NODES / 128) MFMA-GEMM blocks (128 rows each)

typedef unsigned int uint;
typedef unsigned short ushort;
typedef __attribute__((ext_vector_type(8))) short bf16x8;
typedef __attribute__((ext_vector_type(4))) float f32x4;

__device__ inline ushort f2bf(float f) {   // RNE float->bf16
    uint u = __float_as_uint(f);
    u += 0x7fff + ((u >> 16) & 1);
    return (ushort)(u >> 16);
}
__device__ inline float bf2f(ushort h) {
    return __uint_as_float(((uint)h) << 16);
}

// ---------------- K0: init per-bucket bump cursors ----------------

__global__ __launch_bounds__(1024) void k_init(int* __restrict__ gcur) {
    int t = threadIdx.x;
    if (t < NBUCK) gcur[t] = t * CAP;
}

// ------- K1 fat kernel: blocks [0,256) bucket-scatter edges; rest do h1 = x@W1 (MFMA) -------
// Scatter branch: LDS histogram -> one global atomicAdd per bucket (window reserve)
// -> re-read chunk -> scatter into reserved windows. Bucket regions stay contiguous.

__global__ __launch_bounds__(256) void k_scatter_fat(const int* __restrict__ src,
                                                     const int* __restrict__ dst,
                                                     int* __restrict__ gcur,
                                                     int* __restrict__ tmp,
                                                     const float* __restrict__ x,
                                                     const float* __restrict__ W1,
                                                     ushort* __restrict__ h1b) {
    __shared__ uint smu[4096];  // 16 KiB: scatter hist/cursors  |  W1 bf16 fragments
    int t = threadIdx.x;
    if (blockIdx.x < NBLK_B) {
        int* h = (int*)smu;
        for (int b = t; b < NBUCK; b += 256) h[b] = 0;
        __syncthreads();
        int base = blockIdx.x * CHUNK;
        int end = base + CHUNK;
        // pass 1: histogram this chunk (2 independent loads in flight)
        for (int i = base + t; i < end; i += 512) {
            int d0 = dst[i];
            int ok1 = (i + 256 < end);
            int d1 = ok1 ? dst[i + 256] : 0;
            atomicAdd(&h[d0 >> 7], 1);
            if (ok1) atomicAdd(&h[d1 >> 7], 1);
        }
        __syncthreads();
        // reserve windows: one global atomic per non-empty bucket
        for (int b = t; b < NBUCK; b += 256) {
            int c = h[b];
            h[b] = (c > 0) ? atomicAdd(&gcur[b], c) : 0;
        }
        __syncthreads();
        // pass 2: re-read chunk (L2-hot), scatter into reserved windows
        for (int i = base + t; i < end; i += 512) {
            int s0 = src[i], d0 = dst[i];
            int ok1 = (i + 256 < end);
            int s1 = 0, d1 = 0;
            if (ok1) { s1 = src[i + 256]; d1 = dst[i + 256]; }
            int p0 = atomicAdd(&h[d0 >> 7], 1);
            tmp[p0] = (s0 << 7) | (d0 & 127);
            if (ok1) {
                int p1 = atomicAdd(&h[d1 >> 7], 1);
                tmp[p1] = (s1 << 7) | (d1 & 127);
            }
        }
    } else {
        // h1 = x @ W1 via mfma_f32_16x16x32_bf16. 128 rows/block (2 row-groups per
        // W1 staging). Fragment layouts: A row=lane&15, k=(lane>>4)*8+j; B likewise,
        // col=lane&15; D col=lane&15, row=(lane>>4)*4+reg (guide-verified).
        int g = blockIdx.x - NBLK_B;
        // build W1 bf16 B-fragments in LDS: smu[((kt*4+ct)*64 + lane)*4 + dw]
#pragma unroll
        for (int i = 0; i < 16; ++i) {
            int lin = i * 256 + t;           // 0..4095
            int frag = lin >> 8;             // 0..15 = kt*4+ct
            int lane_ = (lin >> 2) & 63;
            int dw = lin & 3;
            int k = ((frag >> 2) << 5) + ((lane_ >> 4) << 3) + dw * 2;
            int c = ((frag & 3) << 4) + (lane_ & 15);
            smu[lin] = ((uint)f2bf(W1[(k + 1) * HID_C + c]) << 16) | f2bf(W1[k * HID_C + c]);
        }
        __syncthreads();
        int wave = t >> 6, lane = t & 63;
        bf16x8 bfr[4][4];
#pragma unroll
        for (int kt = 0; kt < 4; ++kt)
#pragma unroll
            for (int ct = 0; ct < 4; ++ct)
                bfr[kt][ct] = *(bf16x8*)&smu[((kt * 4 + ct) * 64 + lane) * 4];
        int kbase = (lane >> 4) * 8;
#pragma unroll
        for (int it = 0; it < 2; ++it) {
            int row0 = g * 128 + it * 64 + wave * 16;
            int arow = row0 + (lane & 15);
            if (arow > N_NODES - 1) arow = N_NODES - 1;  // tail: clamp loads, guard stores
            f32x4 acc0 = {0.f, 0.f, 0.f, 0.f}, acc1 = {0.f, 0.f, 0.f, 0.f};
            f32x4 acc2 = {0.f, 0.f, 0.f, 0.f}, acc3 = {0.f, 0.f, 0.f, 0.f};
#pragma unroll
            for (int kt = 0; kt < 4; ++kt) {
                const float* xp = &x[arow * IN_C + kt * 32 + kbase];
                float4 u0 = *(const float4*)xp;
                float4 u1 = *(const float4*)(xp + 4);
                union { uint u[4]; bf16x8 v; } A;
                A.u[0] = ((uint)f2bf(u0.y) << 16) | f2bf(u0.x);
                A.u[1] = ((uint)f2bf(u0.w) << 16) | f2bf(u0.z);
                A.u[2] = ((uint)f2bf(u1.y) << 16) | f2bf(u1.x);
                A.u[3] = ((uint)f2bf(u1.w) << 16) | f2bf(u1.z);
                acc0 = __builtin_amdgcn_mfma_f32_16x16x32_bf16(A.v, bfr[kt][0], acc0, 0, 0, 0);
                acc1 = __builtin_amdgcn_mfma_f32_16x16x32_bf16(A.v, bfr[kt][1], acc1, 0, 0, 0);
                acc2 = __builtin_amdgcn_mfma_f32_16x16x32_bf16(A.v, bfr[kt][2], acc2, 0, 0, 0);
                acc3 = __builtin_amdgcn_mfma_f32_16x16x32_bf16(A.v, bfr[kt][3], acc3, 0, 0, 0);
            }
            int rbase = row0 + ((lane >> 4) << 2);
            int cb = lane & 15;
#pragma unroll
            for (int r = 0; r < 4; ++r) {
                int row = rbase + r;
                if (row < N_NODES) {
                    h1b[row * HID_C + cb]      = f2bf(acc0[r]);
                    h1b[row * HID_C + 16 + cb] = f2bf(acc1[r]);
                    h1b[row * HID_C + 32 + cb] = f2bf(acc2[r]);
                    h1b[row * HID_C + 48 + cb] = f2bf(acc3[r]);
                }
            }
        }
    }
}

// ------- K2: per-bucket CSR build + h1 prescale (h~ = bf16(dinv*h1)) -------
// Bucket b's edges live in tmp[b*CAP, gcur[b]). Emits row_start/row_end/dinv/eidx.

__global__ __launch_bounds__(256) void k_csr_build(const int* __restrict__ gcur,
                                                   const int* __restrict__ tmp,
                                                   int* __restrict__ row_start,
                                                   int* __restrict__ row_end,
                                                   int* __restrict__ eidx,
                                                   float* __restrict__ dinv,
                                                   uint* __restrict__ h1u) {
    __shared__ int h[128];
    __shared__ int cur[128];
    __shared__ float dl[128];
    int b = blockIdx.x, t = threadIdx.x;
    int e0 = b * CAP, e1 = gcur[b];
    if (t < 128) h[t] = 0;
    int pk[MAXPT];
#pragma unroll
    for (int k = 0; k < MAXPT; ++k) {
        int i = e0 + k * 256 + t;
        pk[k] = (i < e1) ? tmp[i] : -1;
    }
    __syncthreads();
#pragma unroll
    for (int k = 0; k < MAXPT; ++k)
        if (pk[k] >= 0) atomicAdd(&h[pk[k] & 127], 1);
    __syncthreads();
    int d0 = (t < 128) ? h[t] : 0;
    for (int o = 1; o < 128; o <<= 1) {
        int u = (t >= o && t < 128) ? h[t - o] : 0;
        __syncthreads();
        if (t < 128) h[t] += u;
        __syncthreads();
    }
    int g = b * 128 + t;
    if (t < 128 && g < N_NODES) {
        int ex = h[t] - d0;
        row_start[g] = e0 + ex;
        row_end[g]   = e0 + h[t];
        cur[t]       = e0 + ex;
        float dv = rsqrtf((float)(d0 + 1));  // +1 self loop
        dinv[g] = dv;
        dl[t] = dv;
    }
    __syncthreads();
#pragma unroll
    for (int k = 0; k < MAXPT; ++k)
        if (pk[k] >= 0) {
            int p = atomicAdd(&cur[pk[k] & 127], 1);
            eidx[p] = pk[k] >> 7;
        }
    // prescale this bucket's h1 rows by dinv (bf16x2 per uint)
    int bu = b * 128 * (HID_C / 2);
    for (int i = t; i < 128 * (HID_C / 2); i += 256) {
        int rl = i >> 5;
        int gg = b * 128 + rl;
        if (gg < N_NODES) {
            float dv = dl[rl];
            uint v = h1u[bu + i];
            float lo = __uint_as_float(v << 16) * dv;
            float hi = __uint_as_float(v & 0xffff0000u) * dv;
            h1u[bu + i] = ((uint)f2bf(hi) << 16) | f2bf(lo);
        }
    }
}

// ------- K3: gather layer 1 (prescaled h~) + relu + FUSED gemm2 -> hs2 (bf16) -------
// 256 thr; 4 node-groups of 8 per block (W2 staged once); 32 lanes/node; 8-deep unroll.

__global__ __launch_bounds__(256) void k_gather1f(const int* __restrict__ row_start,
                                                  const int* __restrict__ row_end,
                                                  const int* __restrict__ eidx,
                                                  const uint* __restrict__ h1u,
                                                  const float* __restrict__ dinv,
                                                  const float* __restrict__ b1,
                                                  const float* __restrict__ W2,
                                                  ushort* __restrict__ hs2b) {
    __shared__ float a1s[8][HID_C];       // 2 KiB
    __shared__ float W2s[HID_C * OUT_C];  // 8 KiB
    int t = threadIdx.x;
    for (int i = t; i < HID_C * OUT_C; i += 256) W2s[i] = W2[i];
    int sub = t & 31;
    int r = t >> 5;  // 0..7
    float2 bb = *(const float2*)&b1[sub * 2];

    for (int g = 0; g < 4; ++g) {
        int node = (blockIdx.x * 4 + g) * 8 + r;  // N_NODES = 3125*4*8 exact
        float dn = dinv[node];
        int rs = row_start[node];
        int re = row_end[node];
        uint su = h1u[node * 32 + sub];           // self term: already dinv-scaled
        float accx = __uint_as_float(su << 16);
        float accy = __uint_as_float(su & 0xffff0000u);
        int j = rs;
        for (; j + 7 < re; j += 8) {
            int s0 = eidx[j],     s1 = eidx[j + 1], s2 = eidx[j + 2], s3 = eidx[j + 3];
            int s4 = eidx[j + 4], s5 = eidx[j + 5], s6 = eidx[j + 6], s7 = eidx[j + 7];
            uint u0 = h1u[s0 * 32 + sub], u1 = h1u[s1 * 32 + sub];
            uint u2 = h1u[s2 * 32 + sub], u3 = h1u[s3 * 32 + sub];
            uint u4 = h1u[s4 * 32 + sub], u5 = h1u[s5 * 32 + sub];
            uint u6 = h1u[s6 * 32 + sub], u7 = h1u[s7 * 32 + sub];
            accx += (__uint_as_float(u0 << 16) + __uint_as_float(u1 << 16))
                  + (__uint_as_float(u2 << 16) + __uint_as_float(u3 << 16))
                  + (__uint_as_float(u4 << 16) + __uint_as_float(u5 << 16))
                  + (__uint_as_float(u6 << 16) + __uint_as_float(u7 << 16));
            accy += (__uint_as_float(u0 & 0xffff0000u) + __uint_as_float(u1 & 0xffff0000u))
                  + (__uint_as_float(u2 & 0xffff0000u) + __uint_as_float(u3 & 0xffff0000u))
                  + (__uint_as_float(u4 & 0xffff0000u) + __uint_as_float(u5 & 0xffff0000u))
                  + (__uint_as_float(u6 & 0xffff0000u) + __uint_as_float(u7 & 0xffff0000u));
        }
        for (; j + 3 < re; j += 4) {
            int s0 = eidx[j], s1 = eidx[j + 1], s2 = eidx[j + 2], s3 = eidx[j + 3];
            uint u0 = h1u[s0 * 32 + sub], u1 = h1u[s1 * 32 + sub];
            uint u2 = h1u[s2 * 32 + sub], u3 = h1u[s3 * 32 + sub];
            accx += (__uint_as_float(u0 << 16) + __uint_as_float(u1 << 16))
                  + (__uint_as_float(u2 << 16) + __uint_as_float(u3 << 16));
            accy += (__uint_as_float(u0 & 0xffff0000u) + __uint_as_float(u1 & 0xffff0000u))
                  + (__uint_as_float(u2 & 0xffff0000u) + __uint_as_float(u3 & 0xffff0000u));
        }
        for (; j < re; ++j) {
            uint u = h1u[eidx[j] * 32 + sub];
            accx += __uint_as_float(u << 16);
            accy += __uint_as_float(u & 0xffff0000u);
        }
        __syncthreads();  // a1s free (W2 staged / previous gemm2 done)
        a1s[r][sub * 2 + 0] = fmaxf(dn * accx + bb.x, 0.f);
        a1s[r][sub * 2 + 1] = fmaxf(dn * accy + bb.y, 0.f);
        __syncthreads();

        // fused gemm2: thread (r, o=sub): hs2[node][o] = dn * sum_k a1s[r][k] * W2[k][o]
        float sum = 0.f;
#pragma unroll 8
        for (int k = 0; k < HID_C; ++k)
            sum += a1s[r][k] * W2s[k * OUT_C + sub];
        hs2b[node * OUT_C + sub] = f2bf(dn * sum);
    }
}

// ------- K4: gather layer 2 (bf16 hs2, prescaled) + epilogue -> out -------
// 256 thr, 8 nodes/block, 32 lanes/node (lane = out channel). 8-deep unroll.

__global__ __launch_bounds__(256) void k_gather2(const int* __restrict__ row_start,
                                                 const int* __restrict__ row_end,
                                                 const int* __restrict__ eidx,
                                                 const ushort* __restrict__ hs2b,
                                                 const float* __restrict__ dinv,
                                                 const float* __restrict__ b2,
                                                 float* __restrict__ out) {
    int t = threadIdx.x;
    int sub = t & 31;
    int node = blockIdx.x * 8 + (t >> 5);  // N_NODES divisible by 8

    float dn = dinv[node];
    int rs = row_start[node];
    int re = row_end[node];
    float acc = bf2f(hs2b[node * OUT_C + sub]);  // self loop
    int j = rs;
    for (; j + 7 < re; j += 8) {
        int s0 = eidx[j],     s1 = eidx[j + 1], s2 = eidx[j + 2], s3 = eidx[j + 3];
        int s4 = eidx[j + 4], s5 = eidx[j + 5], s6 = eidx[j + 6], s7 = eidx[j + 7];
        float v0 = bf2f(hs2b[s0 * OUT_C + sub]);
        float v1 = bf2f(hs2b[s1 * OUT_C + sub]);
        float v2 = bf2f(hs2b[s2 * OUT_C + sub]);
        float v3 = bf2f(hs2b[s3 * OUT_C + sub]);
        float v4 = bf2f(hs2b[s4 * OUT_C + sub]);
        float v5 = bf2f(hs2b[s5 * OUT_C + sub]);
        float v6 = bf2f(hs2b[s6 * OUT_C + sub]);
        float v7 = bf2f(hs2b[s7 * OUT_C + sub]);
        acc += ((v0 + v1) + (v2 + v3)) + ((v4 + v5) + (v6 + v7));
    }
    for (; j + 3 < re; j += 4) {
        int s0 = eidx[j], s1 = eidx[j + 1], s2 = eidx[j + 2], s3 = eidx[j + 3];
        float v0 = bf2f(hs2b[s0 * OUT_C + sub]);
        float v1 = bf2f(hs2b[s1 * OUT_C + sub]);
        float v2 = bf2f(hs2b[s2 * OUT_C + sub]);
        float v3 = bf2f(hs2b[s3 * OUT_C + sub]);
        acc += (v0 + v1) + (v2 + v3);
    }
    for (; j < re; ++j) acc += bf2f(hs2b[eidx[j] * OUT_C + sub]);

    out[node * OUT_C + sub] = dn * acc + b2[sub];
}

extern "C" void kernel_launch(void* const* d_in, const int* in_sizes, int n_in,
                              void* d_out, int out_size, void* d_ws, size_t ws_size,
                              hipStream_t stream) {
    const float* x  = (const float*)d_in[0];
    const int* ei   = (const int*)d_in[1];   // [2, E]: src then dst
    const float* W1 = (const float*)d_in[2];
    const float* b1 = (const float*)d_in[3];
    const float* W2 = (const float*)d_in[4];
    const float* b2 = (const float*)d_in[5];
    float* out = (float*)d_out;

    const int* src = ei;
    const int* dst = ei + N_EDGES;

    // workspace layout (bytes), total ~36.8 MB
    char* ws = (char*)d_ws;
    int*    row_start = (int*)(ws + 0);            //   400,000
    int*    row_end   = (int*)(ws + 400000);       //   400,000
    float*  dinv      = (float*)(ws + 800000);     //   400,000
    int*    gcur      = (int*)(ws + 1200000);      //     4,096
    int*    tmp       = (int*)(ws + 1204096);      // 8,007,680 (NBUCK*CAP*4)
    int*    eidx      = (int*)(ws + 9211776);      // 8,007,680
    ushort* h1b       = (ushort*)(ws + 17219456);  // 12,800,000 (bf16)
    ushort* hs2b      = (ushort*)(ws + 30019456);  //  6,400,000 (bf16)

    k_init<<<1, 1024, 0, stream>>>(gcur);

    k_scatter_fat<<<NBLK_B + MF_BLKS, 256, 0, stream>>>(src, dst, gcur, tmp, x, W1, h1b);

    k_csr_build<<<NBUCK, 256, 0, stream>>>(gcur, tmp, row_start, row_end, eidx, dinv,
                                           (uint*)h1b);

    k_gather1f<<<N_NODES / 32, 256, 0, stream>>>(row_start, row_end, eidx, (const uint*)h1b,
                                                 dinv, b1, W2, hs2b);
    k_gather2<<<N_NODES / 8, 256, 0, stream>>>(row_start, row_end, eidx, hs2b, dinv, b2, out);
}